// Round 6
// baseline (301.067 us; speedup 1.0000x reference)
//
#include <hip/hip_runtime.h>
#include <stdint.h>

// ---------------------------------------------------------------------------
// Single-head attention, B=4, S=2048, D=1024, fp32 in/out. bf16 MFMA pipeline.
//
//  0. cvt fp32->bf16: query,key -> qf,kf; weights -> Wb; bias copy
//  1. [q;k] = [qf;kf] @ [Wq;Wk]^T + b    (z=2 batched)
//  2. cvt value -> vf (overlays dead qf)
//  3. vT = Wv @ vf^T + bv                 [1024,8192]
//  4. P  = q @ k^T / 32 (z=4)             [4,2048,2048] (overlays qf/kf/vf)
//  5. softmax rows of P in place
//  6. o  = P @ vT^T (z=4)                 (overlays dead q)
//  7. out= o @ Wo^T + bo -> d_out (fp32)
//
// GEMM engine v3 (T1+T2+T4+T5, LDS-traffic-balanced):
//   BM=256 BN=256 BK=32, 512 thr = 8 waves (2M x 4N), per-wave 128x64
//   (per CU per K-tile: MFMA 1242cy >= LDS-read 1152cy -- wave-tile chosen so
//   the shared LDS pipe no longer exceeds the MFMA pipe, unlike 64x64).
//   3-buffer LDS ring (3 x 32KB = 96KB), prefetch dist 2.
//   ONE raw barrier + ONE counted s_waitcnt vmcnt(4) per K-tile (never drains
//   mid-loop; vmcnt BEFORE barrier makes all waves' staging of tile t visible
//   to everyone after the barrier). Interior (12 ds_read_b128 + 32 MFMA +
//   4 global_load_lds) is compiler-scheduled with fine lgkmcnt.
//   LDS layout: row-pair [r>>1][(r&1)*4+u] (128B pitch) + su ^= (srow&7)
//   swizzle, applied to pre-swizzled global SOURCE (rule #21) and ds_read
//   address -> 2-way per quarter-wave = free.
// ---------------------------------------------------------------------------

typedef __bf16  bf16x8 __attribute__((ext_vector_type(8)));
typedef float   f32x4  __attribute__((ext_vector_type(4)));
typedef unsigned int u32x4 __attribute__((ext_vector_type(4)));

__device__ __forceinline__ unsigned short bf16_rne(float f) {
  unsigned int u = __builtin_bit_cast(unsigned int, f);
  u += 0x7FFFu + ((u >> 16) & 1u);
  return (unsigned short)(u >> 16);
}
__device__ __forceinline__ unsigned int pack2(float a, float b) {
  return (unsigned int)bf16_rne(a) | ((unsigned int)bf16_rne(b) << 16);
}
__device__ __forceinline__ void async16(const unsigned short* g, unsigned short* l) {
  __builtin_amdgcn_global_load_lds(
      (const __attribute__((address_space(1))) unsigned int*)g,
      (__attribute__((address_space(3))) unsigned int*)l,
      16, 0, 0);
}

#define FENCE() asm volatile("" ::: "memory")
#define BAR()   __builtin_amdgcn_s_barrier()

// ---------------------------------------------------------------------------
// C[z][m][n] = scale * sum_k A[z][m][k] * B[z][n][k]  (+ bias)
// M % 256 == 0, N % 256 == 0, K % 32 == 0, K >= 96.
// ---------------------------------------------------------------------------
template<int OUT_F32>
__global__ __launch_bounds__(512, 2) void gemm256(
    const unsigned short* __restrict__ A, const unsigned short* __restrict__ B,
    void* __restrict__ Cp,
    int K, int lda, int ldb, int ldc,
    long sAz, long sBz, long sCz, long sBiasZ,
    float scale, const float* __restrict__ bias, int bias_mode)
{
  __shared__ unsigned short lds[3 * 16384];   // per buf: A 8192 + B 8192 ushorts

  // ---- T1: XCD-chunked bijective remap (m204), work linearized x-fastest.
  const int nx   = gridDim.x, ny = gridDim.y;
  const int nwg  = nx * ny * gridDim.z;
  const int orig = (blockIdx.z * ny + blockIdx.y) * nx + blockIdx.x;
  const int xcd  = orig & 7, loc = orig >> 3;
  const int qq   = nwg >> 3, rr = nwg & 7;
  const int w    = (xcd < rr ? xcd * (qq + 1) : rr * (qq + 1) + (xcd - rr) * qq) + loc;
  const int bxi  = w % nx;
  const int byi  = (w / nx) % ny;
  const int bzi  = w / (nx * ny);

  const int tid  = threadIdx.x;
  const int lane = tid & 63;
  const int wid  = tid >> 6;                  // 0..7
  const int bm   = byi * 256;
  const int bn   = bxi * 256;
  const long z   = bzi;

  const unsigned short* Az = A + z * sAz;
  const unsigned short* Bz = B + z * sBz;

  const int wm = wid >> 2;                    // 0..1  (128 rows each)
  const int wn = wid & 3;                     // 0..3  (64 cols each)
  const int al = lane & 15;
  const int ah = lane >> 4;

  // ---- staging source map (pair-layout + swizzle, pre-applied to source).
  // unit_lin = pass*512 + tid; srow = unit_lin>>3; su_phys = tid&7;
  // su_log = su_phys ^ (srow&7); global row = srow*2 + (su_log>>2),
  // k elem = (su_log&3)*8.
  const int t8  = tid >> 3;                   // 0..63 (= srow pass0)
  const int sul = (tid & 7) ^ (t8 & 7);       // su_log
  const int dr  = sul >> 2;                   // row parity
  const int kc  = (sul & 3) << 3;             // k elem offset 0..24
  const unsigned short* Ap0 = Az + (long)(bm + t8 * 2 + dr) * lda + kc;
  const unsigned short* Ap1 = Ap0 + (long)128 * lda;
  const unsigned short* Bp0 = Bz + (long)(bn + t8 * 2 + dr) * ldb + kc;
  const unsigned short* Bp1 = Bp0 + (long)128 * ldb;

  // per-wave LDS dest offsets (ushorts; wave-uniform, HW adds lane*16B)
  const int dA0 = wid * 512, dA1 = wid * 512 + 4096;
  const int dB0 = 8192 + wid * 512, dB1 = 8192 + wid * 512 + 4096;

  // ---- fragment read map: row = base + al -> srow = base/2 + (al>>1),
  // su_log = (al&1)*4 + ah, su_phys = su_log ^ (srow&7), (srow&7)==(al>>1).
  const int sup     = (((al & 1) << 2) | ah) ^ (al >> 1);
  const int laneoff = (al >> 1) * 64 + sup * 8;
  const int aboff   = wm * 4096 + laneoff;           // + m*512
  const int bboff   = 8192 + wn * 2048 + laneoff;    // + n*512

  f32x4 acc[8][4] = {};
  const int nkt = K >> 5;

#define STAGE(kt, buf) { const long ko = (long)(kt) << 5; \
    const int bb_ = (buf) * 16384; \
    async16(Ap0 + ko, lds + bb_ + dA0); \
    async16(Ap1 + ko, lds + bb_ + dA1); \
    async16(Bp0 + ko, lds + bb_ + dB0); \
    async16(Bp1 + ko, lds + bb_ + dB1); }

  // prologue: tiles 0,1 -> bufs 0,1 (8 loads in flight per wave)
  STAGE(0, 0); STAGE(1, 1);

  int cur = 0;
  for (int t = 0; t < nkt; ++t) {
    // tile t resident across ALL waves: each wave allows only its 4 newest
    // (tile t+1) outstanding, then barrier -> everyone's t-stages landed.
    if (t + 1 < nkt) asm volatile("s_waitcnt vmcnt(4)" ::: "memory");
    else             asm volatile("s_waitcnt vmcnt(0)" ::: "memory");
    BAR(); FENCE();

    const int stb = (cur >= 1) ? cur - 1 : cur + 2;   // (t+2)%3
    if (t + 2 < nkt) STAGE(t + 2, stb);

    const unsigned short* ab = lds + cur * 16384 + aboff;
    const unsigned short* bb = lds + cur * 16384 + bboff;

    bf16x8 a0 = *(const bf16x8*)(ab);
    bf16x8 a1 = *(const bf16x8*)(ab + 512);
    bf16x8 a2 = *(const bf16x8*)(ab + 1024);
    bf16x8 a3 = *(const bf16x8*)(ab + 1536);
    bf16x8 a4 = *(const bf16x8*)(ab + 2048);
    bf16x8 a5 = *(const bf16x8*)(ab + 2560);
    bf16x8 a6 = *(const bf16x8*)(ab + 3072);
    bf16x8 a7 = *(const bf16x8*)(ab + 3584);
    bf16x8 b0 = *(const bf16x8*)(bb);
    bf16x8 b1 = *(const bf16x8*)(bb + 512);
    bf16x8 b2 = *(const bf16x8*)(bb + 1024);
    bf16x8 b3 = *(const bf16x8*)(bb + 1536);

    __builtin_amdgcn_s_setprio(1);
#define MMR(m, av) \
    acc[m][0] = __builtin_amdgcn_mfma_f32_16x16x32_bf16(av, b0, acc[m][0], 0, 0, 0); \
    acc[m][1] = __builtin_amdgcn_mfma_f32_16x16x32_bf16(av, b1, acc[m][1], 0, 0, 0); \
    acc[m][2] = __builtin_amdgcn_mfma_f32_16x16x32_bf16(av, b2, acc[m][2], 0, 0, 0); \
    acc[m][3] = __builtin_amdgcn_mfma_f32_16x16x32_bf16(av, b3, acc[m][3], 0, 0, 0);
    MMR(0, a0) MMR(1, a1) MMR(2, a2) MMR(3, a3)
    MMR(4, a4) MMR(5, a5) MMR(6, a6) MMR(7, a7)
#undef MMR
    __builtin_amdgcn_s_setprio(0);

    cur = (cur == 2) ? 0 : cur + 1;
  }

  // Epilogue. C/D layout (m89/m91): col = lane&15, row = (lane>>4)*4 + j
  #pragma unroll
  for (int m = 0; m < 8; ++m) {
    #pragma unroll
    for (int n = 0; n < 4; ++n) {
      #pragma unroll
      for (int j = 0; j < 4; ++j) {
        const int grow = bm + wm * 128 + m * 16 + ah * 4 + j;
        const int gcol = bn + wn * 64 + n * 16 + al;
        float v = acc[m][n][j] * scale;
        if (bias_mode == 1)      v += bias[z * sBiasZ + gcol];
        else if (bias_mode == 2) v += bias[z * sBiasZ + grow];
        const long idx = z * sCz + (long)grow * ldc + gcol;
        if (OUT_F32) ((float*)Cp)[idx] = v;
        else         ((unsigned short*)Cp)[idx] = bf16_rne(v);
      }
    }
  }
}

// ---------------------------------------------------------------------------
__global__ __launch_bounds__(256) void cvt_f32_bf16(
    const float* __restrict__ in, unsigned short* __restrict__ out, int n8)
{
  const int i = blockIdx.x * 256 + threadIdx.x;
  if (i >= n8) return;
  f32x4 a = *(const f32x4*)(in + (long)i * 8);
  f32x4 b = *(const f32x4*)(in + (long)i * 8 + 4);
  u32x4 w;
  w[0] = pack2(a[0], a[1]); w[1] = pack2(a[2], a[3]);
  w[2] = pack2(b[0], b[1]); w[3] = pack2(b[2], b[3]);
  *(u32x4*)(out + (long)i * 8) = w;
}

__global__ __launch_bounds__(256) void copy_bias2(
    const float* __restrict__ b0, const float* __restrict__ b1, float* __restrict__ dst)
{
  const int t = blockIdx.x * 256 + threadIdx.x;
  if (t < 1024)       dst[t] = b0[t];
  else if (t < 2048)  dst[t] = b1[t - 1024];
}

// ---------------------------------------------------------------------------
__global__ __launch_bounds__(256) void softmax_inplace(unsigned short* __restrict__ P) {
  const long row = blockIdx.x;
  unsigned short* pr = P + row * 2048;
  const int tid = threadIdx.x;

  u32x4 raw = *(const u32x4*)&pr[tid * 8];
  float s[8];
  #pragma unroll
  for (int i = 0; i < 4; ++i) {
    unsigned int u = raw[i];
    s[2 * i]     = __builtin_bit_cast(float, u << 16);
    s[2 * i + 1] = __builtin_bit_cast(float, u & 0xFFFF0000u);
  }
  float m = s[0];
  #pragma unroll
  for (int i = 1; i < 8; ++i) m = fmaxf(m, s[i]);
  #pragma unroll
  for (int off = 32; off >= 1; off >>= 1) m = fmaxf(m, __shfl_xor(m, off));

  __shared__ float redm[4], reds[4];
  const int wid = tid >> 6, lane = tid & 63;
  if (lane == 0) redm[wid] = m;
  __syncthreads();
  m = fmaxf(fmaxf(redm[0], redm[1]), fmaxf(redm[2], redm[3]));

  float e[8], sum = 0.f;
  #pragma unroll
  for (int i = 0; i < 8; ++i) { e[i] = __expf(s[i] - m); sum += e[i]; }
  #pragma unroll
  for (int off = 32; off >= 1; off >>= 1) sum += __shfl_xor(sum, off);
  if (lane == 0) reds[wid] = sum;
  __syncthreads();
  sum = reds[0] + reds[1] + reds[2] + reds[3];
  const float inv = 1.0f / sum;

  u32x4 outw;
  #pragma unroll
  for (int i = 0; i < 4; ++i) outw[i] = pack2(e[2 * i] * inv, e[2 * i + 1] * inv);
  *(u32x4*)&pr[tid * 8] = outw;
}

// ---------------------------------------------------------------------------
extern "C" void kernel_launch(void* const* d_in, const int* in_sizes, int n_in,
                              void* d_out, int out_size, void* d_ws, size_t ws_size,
                              hipStream_t stream) {
  const float* query = (const float*)d_in[0];
  const float* key_  = (const float*)d_in[1];
  const float* value = (const float*)d_in[2];
  const float* Wq    = (const float*)d_in[3];
  const float* bq    = (const float*)d_in[4];
  const float* Wk    = (const float*)d_in[5];
  const float* bk    = (const float*)d_in[6];
  const float* Wv    = (const float*)d_in[7];
  const float* bv    = (const float*)d_in[8];
  const float* Wo    = (const float*)d_in[9];
  const float* bo    = (const float*)d_in[10];

  unsigned short* ws = (unsigned short*)d_ws;
  unsigned short* qf = ws;                        // [8192][1024] -> vf -> P lower
  unsigned short* kf = ws + 8388608;              // [8192][1024] -> P upper
  unsigned short* vf = ws;                        // overlays dead qf
  unsigned short* P  = ws;                        // [4][2048][2048]
  unsigned short* q  = ws + 16777216;             // [2][8.4M] q,k -> later o
  unsigned short* vT = ws + 33554432;             // [1024][8192]
  unsigned short* Wb = ws + 41943040;             // 4 x [1024][1024] bf16
  float*          bqk= (float*)(ws + 46137344);   // [2][1024] fp32
  unsigned short* o  = q;                         // overlays dead q

  const dim3 blk(256), blk8(512);

  // 0: conversions
  cvt_f32_bf16<<<dim3(512), blk, 0, stream>>>(Wq, Wb,            131072);
  cvt_f32_bf16<<<dim3(512), blk, 0, stream>>>(Wk, Wb + 1048576,  131072);
  cvt_f32_bf16<<<dim3(512), blk, 0, stream>>>(Wv, Wb + 2097152,  131072);
  cvt_f32_bf16<<<dim3(512), blk, 0, stream>>>(Wo, Wb + 3145728,  131072);
  copy_bias2<<<dim3(8), blk, 0, stream>>>(bq, bk, bqk);
  cvt_f32_bf16<<<dim3(4096), blk, 0, stream>>>(query, qf, 1048576);
  cvt_f32_bf16<<<dim3(4096), blk, 0, stream>>>(key_,  kf, 1048576);

  // 1: [q;k] projections, z=2. M=8192, N=1024, K=1024. 256 blocks.
  gemm256<0><<<dim3(4, 32, 2), blk8, 0, stream>>>(qf, Wb, q,
      1024, 1024, 1024, 1024, 8388608L, 1048576L, 8388608L, 1024L, 1.0f, bqk, 1);

  // 2: convert value (into region freed by qf)
  cvt_f32_bf16<<<dim3(4096), blk, 0, stream>>>(value, vf, 1048576);

  // 3: vT = Wv @ vf^T + bv. M=1024, N=8192, K=1024, bias per-row. 128 blocks.
  gemm256<0><<<dim3(32, 4, 1), blk8, 0, stream>>>(Wb + 2097152, vf, vT,
      1024, 1024, 1024, 8192, 0L, 0L, 0L, 0L, 1.0f, bv, 2);

  // 4: P = q @ k^T / 32, z=4. M=N=2048, K=1024. 256 blocks.
  gemm256<0><<<dim3(8, 8, 4), blk8, 0, stream>>>(q, q + 8388608, P,
      1024, 1024, 1024, 2048, 2097152L, 2097152L, 4194304L, 0L, 0.03125f, nullptr, 0);

  // 5: softmax rows in place (8192 rows x 2048)
  softmax_inplace<<<dim3(8192), blk, 0, stream>>>(P);

  // 6: o = P @ vT^T, z=4. M=2048, N=1024, K=2048. 128 blocks.
  gemm256<0><<<dim3(4, 8, 4), blk8, 0, stream>>>(P, vT, o,
      2048, 2048, 8192, 1024, 4194304L, 2048L, 2097152L, 0L, 1.0f, nullptr, 0);

  // 7: out = o @ Wo^T + bo (fp32 out). M=8192, N=1024, K=1024. 128 blocks.
  gemm256<1><<<dim3(4, 32, 1), blk8, 0, stream>>>(o, Wb + 3145728, d_out,
      1024, 1024, 1024, 1024, 0L, 0L, 0L, 0L, 1.0f, bo, 1);
}

// Round 7
// 272.527 us; speedup vs baseline: 1.1047x; 1.1047x over previous
//
#include <hip/hip_runtime.h>
#include <stdint.h>

// ---------------------------------------------------------------------------
// Single-head attention, B=4, S=2048, D=1024, fp32 in/out. bf16 MFMA pipeline.
//
//  0. cvt fp32->bf16: query,key -> qf,kf; weights -> Wb; bias copy
//  1. [q;k] = [qf;kf] @ [Wq;Wk]^T + b    (z=2 batched)
//  2. cvt value -> vf (overlays dead qf)
//  3. vT = Wv @ vf^T + bv                 [1024,8192]
//  4. P  = q @ k^T / 32 (z=4)             [4,2048,2048] (overlays qf/kf/vf)
//  5. softmax rows of P in place
//  6. o  = P @ vT^T (z=4)                 (overlays dead q)
//  7. out= o @ Wo^T + bo -> d_out (fp32)
//
// GEMM engine v4 (T1+T2+T4+T5 + occupancy-first):
//   BM=128 BN=128 BK=32, 256 thr = 4 waves (2M x 2N), per-wave 64x64.
//   3-buffer LDS ring, 16KB/buffer -> 48KB total => 3 RESIDENT BLOCKS/CU
//   (12 waves = 3/SIMD): cross-block TLP hides barrier/vmcnt stalls (m97's
//   3-blocks/CU evidence; round-6 regression showed 1 block/CU starves).
//   Prefetch dist 2; top-of-iter s_waitcnt vmcnt(4) (tile t+1 in flight,
//   never drains mid-loop); ONE raw barrier per K-tile; interior
//   (8 ds_read_b128 + 16 MFMA + 4 global_load_lds) compiler-scheduled.
//   LDS layout: row-pair [r>>1][(r&1)*4+u] (128B pitch) + su ^= (srow&7)
//   swizzle, applied to pre-swizzled global SOURCE (rule #21) and ds_read
//   address -> conflict-free (0 measured in rounds 5-6).
//   T1: XCD-chunked bijective blockIdx remap (m204), x-fastest.
// ---------------------------------------------------------------------------

typedef __bf16  bf16x8 __attribute__((ext_vector_type(8)));
typedef float   f32x4  __attribute__((ext_vector_type(4)));
typedef unsigned int u32x4 __attribute__((ext_vector_type(4)));

__device__ __forceinline__ unsigned short bf16_rne(float f) {
  unsigned int u = __builtin_bit_cast(unsigned int, f);
  u += 0x7FFFu + ((u >> 16) & 1u);
  return (unsigned short)(u >> 16);
}
__device__ __forceinline__ unsigned int pack2(float a, float b) {
  return (unsigned int)bf16_rne(a) | ((unsigned int)bf16_rne(b) << 16);
}
__device__ __forceinline__ void async16(const unsigned short* g, unsigned short* l) {
  __builtin_amdgcn_global_load_lds(
      (const __attribute__((address_space(1))) unsigned int*)g,
      (__attribute__((address_space(3))) unsigned int*)l,
      16, 0, 0);
}

#define FENCE() asm volatile("" ::: "memory")
#define BAR()   __builtin_amdgcn_s_barrier()

// ---------------------------------------------------------------------------
// C[z][m][n] = scale * sum_k A[z][m][k] * B[z][n][k]  (+ bias)
// M % 128 == 0, N % 128 == 0, K % 32 == 0, K >= 96.
// ---------------------------------------------------------------------------
template<int OUT_F32>
__global__ __launch_bounds__(256, 3) void gemm128(
    const unsigned short* __restrict__ A, const unsigned short* __restrict__ B,
    void* __restrict__ Cp,
    int K, int lda, int ldb, int ldc,
    long sAz, long sBz, long sCz, long sBiasZ,
    float scale, const float* __restrict__ bias, int bias_mode)
{
  __shared__ unsigned short lds[3 * 8192];    // per buf: A 4096 + B 4096 ushorts

  // ---- T1: XCD-chunked bijective remap (m204), work linearized x-fastest.
  const int nx   = gridDim.x, ny = gridDim.y;
  const int nwg  = nx * ny * gridDim.z;
  const int orig = (blockIdx.z * ny + blockIdx.y) * nx + blockIdx.x;
  const int xcd  = orig & 7, loc = orig >> 3;
  const int qq   = nwg >> 3, rr = nwg & 7;
  const int w    = (xcd < rr ? xcd * (qq + 1) : rr * (qq + 1) + (xcd - rr) * qq) + loc;
  const int bxi  = w % nx;
  const int byi  = (w / nx) % ny;
  const int bzi  = w / (nx * ny);

  const int tid  = threadIdx.x;
  const int lane = tid & 63;
  const int wid  = tid >> 6;                  // 0..3
  const int bm   = byi * 128;
  const int bn   = bxi * 128;
  const long z   = bzi;

  const unsigned short* Az = A + z * sAz;
  const unsigned short* Bz = B + z * sBz;

  const int wm = wid >> 1;                    // 0..1 (64 rows each)
  const int wn = wid & 1;                     // 0..1 (64 cols each)
  const int al = lane & 15;
  const int ah = lane >> 4;

  // ---- staging source map (pair-layout + swizzle pre-applied to source).
  // pass p: unit_lin = p*256 + tid; srow = unit_lin>>3; su_phys = tid&7;
  // su_log = su_phys ^ (srow&7); row = srow*2 + (su_log>>2), kc = (su_log&3)*8.
  // pass1 srow = srow0 + 32 -> (srow&7) unchanged -> Ap1 = Ap0 + 64*lda.
  const int t8  = tid >> 3;                   // srow pass0 (0..31)
  const int sul = (tid & 7) ^ (t8 & 7);
  const int dr  = sul >> 2;
  const int kc  = (sul & 3) << 3;
  const unsigned short* Ap0 = Az + (long)(bm + t8 * 2 + dr) * lda + kc;
  const unsigned short* Ap1 = Ap0 + (long)64 * lda;
  const unsigned short* Bp0 = Bz + (long)(bn + t8 * 2 + dr) * ldb + kc;
  const unsigned short* Bp1 = Bp0 + (long)64 * ldb;

  // per-wave LDS dest offsets (wave-uniform; HW adds lane*16B)
  const int dA0 = wid * 512, dA1 = wid * 512 + 2048;
  const int dB0 = 4096 + wid * 512, dB1 = 4096 + wid * 512 + 2048;

  // ---- fragment read map: row = base + al (base mult of 16) ->
  // srow&7 = al>>1; su_log = (al&1)*4 + ah; su_phys = su_log ^ (al>>1).
  const int sup     = (((al & 1) << 2) | ah) ^ (al >> 1);
  const int laneoff = (al >> 1) * 64 + sup * 8;
  const int aboff   = wm * 2048 + laneoff;           // + m*512
  const int bboff   = 4096 + wn * 2048 + laneoff;    // + n*512

  f32x4 acc[4][4] = {};
  const int nkt = K >> 5;

#define STAGE(kt, buf) { const long ko = (long)(kt) << 5; \
    const int bb_ = (buf) * 8192; \
    async16(Ap0 + ko, lds + bb_ + dA0); \
    async16(Ap1 + ko, lds + bb_ + dA1); \
    async16(Bp0 + ko, lds + bb_ + dB0); \
    async16(Bp1 + ko, lds + bb_ + dB1); }

  // prologue: tiles 0,1 -> bufs 0,1 (8 loads in flight per wave)
  STAGE(0, 0); STAGE(1, 1);

  int cur = 0;
  for (int t = 0; t < nkt; ++t) {
    // tile t resident across all waves: allow only tile t+1's 4 loads
    // outstanding, then barrier.
    if (t + 1 < nkt) asm volatile("s_waitcnt vmcnt(4)" ::: "memory");
    else             asm volatile("s_waitcnt vmcnt(0)" ::: "memory");
    BAR(); FENCE();

    const int stb = (cur >= 1) ? cur - 1 : cur + 2;   // (t+2)%3
    if (t + 2 < nkt) STAGE(t + 2, stb);

    const unsigned short* ab = lds + cur * 8192 + aboff;
    const unsigned short* bb = lds + cur * 8192 + bboff;

    bf16x8 a0 = *(const bf16x8*)(ab);
    bf16x8 a1 = *(const bf16x8*)(ab + 512);
    bf16x8 a2 = *(const bf16x8*)(ab + 1024);
    bf16x8 a3 = *(const bf16x8*)(ab + 1536);
    bf16x8 b0 = *(const bf16x8*)(bb);
    bf16x8 b1 = *(const bf16x8*)(bb + 512);
    bf16x8 b2 = *(const bf16x8*)(bb + 1024);
    bf16x8 b3 = *(const bf16x8*)(bb + 1536);

    __builtin_amdgcn_s_setprio(1);
#define MMR(m, av) \
    acc[m][0] = __builtin_amdgcn_mfma_f32_16x16x32_bf16(av, b0, acc[m][0], 0, 0, 0); \
    acc[m][1] = __builtin_amdgcn_mfma_f32_16x16x32_bf16(av, b1, acc[m][1], 0, 0, 0); \
    acc[m][2] = __builtin_amdgcn_mfma_f32_16x16x32_bf16(av, b2, acc[m][2], 0, 0, 0); \
    acc[m][3] = __builtin_amdgcn_mfma_f32_16x16x32_bf16(av, b3, acc[m][3], 0, 0, 0);
    MMR(0, a0) MMR(1, a1) MMR(2, a2) MMR(3, a3)
#undef MMR
    __builtin_amdgcn_s_setprio(0);

    cur = (cur == 2) ? 0 : cur + 1;
  }

  // Epilogue. C/D layout (m89/m91): col = lane&15, row = (lane>>4)*4 + j
  #pragma unroll
  for (int m = 0; m < 4; ++m) {
    #pragma unroll
    for (int n = 0; n < 4; ++n) {
      #pragma unroll
      for (int j = 0; j < 4; ++j) {
        const int grow = bm + wm * 64 + m * 16 + ah * 4 + j;
        const int gcol = bn + wn * 64 + n * 16 + al;
        float v = acc[m][n][j] * scale;
        if (bias_mode == 1)      v += bias[z * sBiasZ + gcol];
        else if (bias_mode == 2) v += bias[z * sBiasZ + grow];
        const long idx = z * sCz + (long)grow * ldc + gcol;
        if (OUT_F32) ((float*)Cp)[idx] = v;
        else         ((unsigned short*)Cp)[idx] = bf16_rne(v);
      }
    }
  }
}

// ---------------------------------------------------------------------------
__global__ __launch_bounds__(256) void cvt_f32_bf16(
    const float* __restrict__ in, unsigned short* __restrict__ out, int n8)
{
  const int i = blockIdx.x * 256 + threadIdx.x;
  if (i >= n8) return;
  f32x4 a = *(const f32x4*)(in + (long)i * 8);
  f32x4 b = *(const f32x4*)(in + (long)i * 8 + 4);
  u32x4 w;
  w[0] = pack2(a[0], a[1]); w[1] = pack2(a[2], a[3]);
  w[2] = pack2(b[0], b[1]); w[3] = pack2(b[2], b[3]);
  *(u32x4*)(out + (long)i * 8) = w;
}

__global__ __launch_bounds__(256) void copy_bias2(
    const float* __restrict__ b0, const float* __restrict__ b1, float* __restrict__ dst)
{
  const int t = blockIdx.x * 256 + threadIdx.x;
  if (t < 1024)       dst[t] = b0[t];
  else if (t < 2048)  dst[t] = b1[t - 1024];
}

// ---------------------------------------------------------------------------
__global__ __launch_bounds__(256) void softmax_inplace(unsigned short* __restrict__ P) {
  const long row = blockIdx.x;
  unsigned short* pr = P + row * 2048;
  const int tid = threadIdx.x;

  u32x4 raw = *(const u32x4*)&pr[tid * 8];
  float s[8];
  #pragma unroll
  for (int i = 0; i < 4; ++i) {
    unsigned int u = raw[i];
    s[2 * i]     = __builtin_bit_cast(float, u << 16);
    s[2 * i + 1] = __builtin_bit_cast(float, u & 0xFFFF0000u);
  }
  float m = s[0];
  #pragma unroll
  for (int i = 1; i < 8; ++i) m = fmaxf(m, s[i]);
  #pragma unroll
  for (int off = 32; off >= 1; off >>= 1) m = fmaxf(m, __shfl_xor(m, off));

  __shared__ float redm[4], reds[4];
  const int wid = tid >> 6, lane = tid & 63;
  if (lane == 0) redm[wid] = m;
  __syncthreads();
  m = fmaxf(fmaxf(redm[0], redm[1]), fmaxf(redm[2], redm[3]));

  float e[8], sum = 0.f;
  #pragma unroll
  for (int i = 0; i < 8; ++i) { e[i] = __expf(s[i] - m); sum += e[i]; }
  #pragma unroll
  for (int off = 32; off >= 1; off >>= 1) sum += __shfl_xor(sum, off);
  if (lane == 0) reds[wid] = sum;
  __syncthreads();
  sum = reds[0] + reds[1] + reds[2] + reds[3];
  const float inv = 1.0f / sum;

  u32x4 outw;
  #pragma unroll
  for (int i = 0; i < 4; ++i) outw[i] = pack2(e[2 * i] * inv, e[2 * i + 1] * inv);
  *(u32x4*)&pr[tid * 8] = outw;
}

// ---------------------------------------------------------------------------
extern "C" void kernel_launch(void* const* d_in, const int* in_sizes, int n_in,
                              void* d_out, int out_size, void* d_ws, size_t ws_size,
                              hipStream_t stream) {
  const float* query = (const float*)d_in[0];
  const float* key_  = (const float*)d_in[1];
  const float* value = (const float*)d_in[2];
  const float* Wq    = (const float*)d_in[3];
  const float* bq    = (const float*)d_in[4];
  const float* Wk    = (const float*)d_in[5];
  const float* bk    = (const float*)d_in[6];
  const float* Wv    = (const float*)d_in[7];
  const float* bv    = (const float*)d_in[8];
  const float* Wo    = (const float*)d_in[9];
  const float* bo    = (const float*)d_in[10];

  unsigned short* ws = (unsigned short*)d_ws;
  unsigned short* qf = ws;                        // [8192][1024] -> vf -> P lower
  unsigned short* kf = ws + 8388608;              // [8192][1024] -> P upper
  unsigned short* vf = ws;                        // overlays dead qf
  unsigned short* P  = ws;                        // [4][2048][2048]
  unsigned short* q  = ws + 16777216;             // [2][8.4M] q,k -> later o
  unsigned short* vT = ws + 33554432;             // [1024][8192]
  unsigned short* Wb = ws + 41943040;             // 4 x [1024][1024] bf16
  float*          bqk= (float*)(ws + 46137344);   // [2][1024] fp32
  unsigned short* o  = q;                         // overlays dead q

  const dim3 blk(256);

  // 0: conversions
  cvt_f32_bf16<<<dim3(512), blk, 0, stream>>>(Wq, Wb,            131072);
  cvt_f32_bf16<<<dim3(512), blk, 0, stream>>>(Wk, Wb + 1048576,  131072);
  cvt_f32_bf16<<<dim3(512), blk, 0, stream>>>(Wv, Wb + 2097152,  131072);
  cvt_f32_bf16<<<dim3(512), blk, 0, stream>>>(Wo, Wb + 3145728,  131072);
  copy_bias2<<<dim3(8), blk, 0, stream>>>(bq, bk, bqk);
  cvt_f32_bf16<<<dim3(4096), blk, 0, stream>>>(query, qf, 1048576);
  cvt_f32_bf16<<<dim3(4096), blk, 0, stream>>>(key_,  kf, 1048576);

  // 1: [q;k] projections, z=2. M=8192, N=1024, K=1024. 1024 blocks.
  gemm128<0><<<dim3(8, 64, 2), blk, 0, stream>>>(qf, Wb, q,
      1024, 1024, 1024, 1024, 8388608L, 1048576L, 8388608L, 1024L, 1.0f, bqk, 1);

  // 2: convert value (into region freed by qf)
  cvt_f32_bf16<<<dim3(4096), blk, 0, stream>>>(value, vf, 1048576);

  // 3: vT = Wv @ vf^T + bv. M=1024, N=8192, K=1024, bias per-row. 512 blocks.
  gemm128<0><<<dim3(64, 8, 1), blk, 0, stream>>>(Wb + 2097152, vf, vT,
      1024, 1024, 1024, 8192, 0L, 0L, 0L, 0L, 1.0f, bv, 2);

  // 4: P = q @ k^T / 32, z=4. M=N=2048, K=1024. 1024 blocks.
  gemm128<0><<<dim3(16, 16, 4), blk, 0, stream>>>(q, q + 8388608, P,
      1024, 1024, 1024, 2048, 2097152L, 2097152L, 4194304L, 0L, 0.03125f, nullptr, 0);

  // 5: softmax rows in place (8192 rows x 2048)
  softmax_inplace<<<dim3(8192), blk, 0, stream>>>(P);

  // 6: o = P @ vT^T, z=4. M=2048, N=1024, K=2048. 512 blocks.
  gemm128<0><<<dim3(8, 16, 4), blk, 0, stream>>>(P, vT, o,
      2048, 2048, 8192, 1024, 4194304L, 2048L, 2097152L, 0L, 1.0f, nullptr, 0);

  // 7: out = o @ Wo^T + bo (fp32 out). M=8192, N=1024, K=1024. 512 blocks.
  gemm128<1><<<dim3(8, 64, 1), blk, 0, stream>>>(o, Wb + 3145728, d_out,
      1024, 1024, 1024, 1024, 0L, 0L, 0L, 0L, 1.0f, bo, 1);
}